// Round 7
// baseline (92.557 us; speedup 1.0000x reference)
//
#include <hip/hip_runtime.h>

// RBFNN L1-distance, round 7: C-in-SGPR, X-only LDS.
// k_sim: 512 blocks x 256 threads (16 row-tiles x 32 col-tiles), full K=512.
//   Lane l = batch row row0+l. Wave w handles 4 consecutive output cols
//   o0..o0+3, whose C rows are WAVE-UNIFORM -> scalar loads into SGPRs
//   (separate pipe, free broadcast as VALU src). X is the only LDS tenant:
//   staged as f4 groups xs[kg*65+row] (pad 65 -> conflict-free writes, reads
//   lane-contiguous), double-buffered, register-prefetched; one ds_read_b128
//   per lane per 4 k, then 32 VALU (v_sub_f32 + v_add_f32 with |.| modifier).
//   Full-K per block -> writes sim directly to S, per-block max to bmax[512].
// k_out: global max over 512 block maxes, out = beta*(max*1.001 - sim).

typedef float f4 __attribute__((ext_vector_type(4)));

#define DIM_K 512
#define DIM_O 512
#define W_DIST 1.001f

__global__ __launch_bounds__(256, 2) void k_sim(const float* __restrict__ X,
                                                const float* __restrict__ C,
                                                float* __restrict__ S,
                                                float* __restrict__ bmax)
{
    // xs[buf][kg*65 + row]: 8 kg-groups (4 k each) x 64 rows, pad 65 f4.
    // writes: lanes 0..7 -> kg 0..7 same srow: dword-bank = (kg*65*4+srow*4)%32
    //         = (4*kg + 4*srow)%32 -> 8 distinct banks x 4-wide: conflict-free.
    // reads: lane l reads xs[kg*65 + l]: 64 contiguous f4 = perfectly banked.
    __shared__ __align__(16) f4 xs[2][8 * 65 + 1];
    const int tid = threadIdx.x;
    const int lane = tid & 63;
    const int wv = __builtin_amdgcn_readfirstlane(tid >> 6); // force wave-uniform
    const int row0 = (blockIdx.x >> 5) * 64;
    const int col0 = (blockIdx.x & 31) * 16;
    const int o0 = col0 + wv * 4;
    const float* Crow = C + o0 * DIM_K; // wave-uniform base -> s_load path

    // staging: thread covers (srow, skg) and (srow+32, skg); coalesced 128B runs
    const int srow = tid >> 3;  // 0..31
    const int skg = tid & 7;    // 0..7
    const float* xg0 = X + (row0 + srow) * DIM_K + skg * 4;
    f4 pre0 = *(const f4*)xg0;
    f4 pre1 = *(const f4*)(xg0 + 32 * DIM_K);

    float acc0 = 0.f, acc1 = 0.f, acc2 = 0.f, acc3 = 0.f;

    for (int t = 0; t < 16; ++t) { // 16 chunks x 32 k
        f4* buf = xs[t & 1];
        buf[skg * 65 + srow] = pre0;
        buf[skg * 65 + srow + 32] = pre1;
        if (t < 15) { // issue next chunk's global loads; land during compute
            const float* xg = xg0 + (t + 1) * 32;
            pre0 = *(const f4*)xg;
            pre1 = *(const f4*)(xg + 32 * DIM_K);
        }
        __syncthreads(); // single barrier per chunk (dbuf: WAR safe, see r7 notes)

        const int kc = t * 32;
#pragma unroll
        for (int h = 0; h < 2; ++h) { // 16-k halves: 64 SGPRs of C data live
            f4 c0[4], c1[4], c2[4], c3[4]; // [o][kg] uniform -> SGPRs
#pragma unroll
            for (int kg = 0; kg < 4; ++kg) {
                const int ko = kc + h * 16 + kg * 4;
                c0[kg] = *(const f4*)(Crow + 0 * DIM_K + ko);
                c1[kg] = *(const f4*)(Crow + 1 * DIM_K + ko);
                c2[kg] = *(const f4*)(Crow + 2 * DIM_K + ko);
                c3[kg] = *(const f4*)(Crow + 3 * DIM_K + ko);
            }
#pragma unroll
            for (int kg = 0; kg < 4; ++kg) {
                const f4 xv = buf[(h * 4 + kg) * 65 + lane]; // ds_read_b128
#pragma unroll
                for (int e = 0; e < 4; ++e) {
                    const float x = xv[e];
                    acc0 += __builtin_fabsf(x - c0[kg][e]); // v_sub + v_add |.|
                    acc1 += __builtin_fabsf(x - c1[kg][e]);
                    acc2 += __builtin_fabsf(x - c2[kg][e]);
                    acc3 += __builtin_fabsf(x - c3[kg][e]);
                }
            }
        }
        __syncthreads(); // protect buf reuse two iterations ahead
    }

    // store: lane l writes sim[row0+l][o0..o0+3] as one dwordx4
    f4 out; out[0] = acc0; out[1] = acc1; out[2] = acc2; out[3] = acc3;
    *(f4*)(S + (row0 + lane) * DIM_O + o0) = out;

    // block max
    float m = fmaxf(fmaxf(acc0, acc1), fmaxf(acc2, acc3));
#pragma unroll
    for (int off = 32; off > 0; off >>= 1)
        m = fmaxf(m, __shfl_xor(m, off, 64));
    __shared__ float wm[4];
    if (lane == 0) wm[tid >> 6] = m;
    __syncthreads();
    if (tid == 0)
        bmax[blockIdx.x] = fmaxf(fmaxf(wm[0], wm[1]), fmaxf(wm[2], wm[3]));
}

__global__ __launch_bounds__(256) void k_out(float* __restrict__ S,
                                             const float* __restrict__ beta,
                                             const float* __restrict__ bmax)
{
    const int tid = threadIdx.x;
    const int lane = tid & 63;
    float m = 0.f;
#pragma unroll
    for (int i = 0; i < 8; ++i) // 512 block maxes
        m = fmaxf(m, bmax[lane + 64 * i]);
#pragma unroll
    for (int off = 32; off > 0; off >>= 1)
        m = fmaxf(m, __shfl_xor(m, off, 64));
    const float shift = m * W_DIST;

    const int f = blockIdx.x * 256 + tid; // f4 index, 131072 total
    f4 s = ((const f4*)S)[f];
    f4 b = ((const f4*)beta)[f & 127];
    f4 r;
    r[0] = b[0] * (shift - s[0]);
    r[1] = b[1] * (shift - s[1]);
    r[2] = b[2] * (shift - s[2]);
    r[3] = b[3] * (shift - s[3]);
    ((f4*)S)[f] = r;
}

extern "C" void kernel_launch(void* const* d_in, const int* in_sizes, int n_in,
                              void* d_out, int out_size, void* d_ws, size_t ws_size,
                              hipStream_t stream) {
    const float* X = (const float*)d_in[0];
    const float* C = (const float*)d_in[1];
    const float* beta = (const float*)d_in[2];
    float* S = (float*)d_out;
    float* bmax = (float*)d_ws; // 512 floats, fully overwritten each call
    k_sim<<<512, 256, 0, stream>>>(X, C, S, bmax);
    k_out<<<512, 256, 0, stream>>>(S, beta, bmax);
}

// Round 8
// 83.433 us; speedup vs baseline: 1.1094x; 1.1094x over previous
//
#include <hip/hip_runtime.h>

// RBFNN L1-distance, round 8: fully register-resident hot loop (k-in-lane).
// k_sim: 2048 blocks x 256 thr. Block = 8 batch rows x 32 cols (4 waves x 8 cols).
//   Wave-tile 8x8; K=512 split across 64 lanes (8 k/lane):
//     X tile = 8 rows x 8 floats/lane = 64 VGPRs, loaded ONCE (coalesced).
//     Per col: C slice 8 floats/lane (2 dwordx4, L2-hot), 128 register-only
//     VALU (v_sub_f32 + v_add_f32 with |.| modifier) -> 8 per-lane partials.
//   Cross-lane reduce per col: per-wave-private LDS transpose (stride 12 ->
//     aligned b128 writes, broadcast b32 reads, conflict-free), 3 xor-shuffles
//     over the k-group bits, keep via cndmask. DS pipe is in-order per wave ->
//     no barrier. Lane l ends holding output (b=l>>3, o=l&7): one coalesced-ish
//     store per wave. NO LDS/SMEM in the 128-inst compute body.
// k_out: reduce 2048 block maxes, out = beta * (max*1.001 - sim) in place.

typedef float f4 __attribute__((ext_vector_type(4)));

#define DIM_K 512
#define DIM_O 512
#define W_DIST 1.001f

__global__ __launch_bounds__(256, 4) void k_sim(const float* __restrict__ X,
                                                const float* __restrict__ C,
                                                float* __restrict__ S,
                                                float* __restrict__ bmax)
{
    __shared__ float part[4][64 * 12]; // 12 KB total; per-wave private slice
    __shared__ float wmx[4];
    const int tid = threadIdx.x;
    const int lane = tid & 63;
    const int wv = tid >> 6;
    const int bt = blockIdx.x >> 4;    // 128 b-tiles (o varies fastest -> X L2-hot)
    const int ob = blockIdx.x & 15;    // 16 col-blocks
    const int b0 = bt * 8;
    const int o0 = ob * 32 + wv * 8;
    const int myb = lane >> 3, myo = lane & 7;

    // X[b0+i][lane*8 + e] -> 64 VGPRs, loaded once
    f4 xa[8], xb[8];
    {
        const float* xp = X + b0 * DIM_K + lane * 8;
#pragma unroll
        for (int i = 0; i < 8; ++i) {
            xa[i] = *(const f4*)(xp + i * DIM_K);
            xb[i] = *(const f4*)(xp + i * DIM_K + 4);
        }
    }

    float* mypart = part[wv];
    float res = 0.f; // lane l accumulates its final (myb, myo) output

#pragma unroll
    for (int oc = 0; oc < 8; ++oc) {
        const float* cp = C + (o0 + oc) * DIM_K + lane * 8;
        const f4 ca = *(const f4*)cp;
        const f4 cb = *(const f4*)(cp + 4);
        f4 aca = {0.f, 0.f, 0.f, 0.f}; // partials rows 0..3
        f4 acb = {0.f, 0.f, 0.f, 0.f}; // partials rows 4..7
#pragma unroll
        for (int e = 0; e < 4; ++e) {
#pragma unroll
            for (int i = 0; i < 4; ++i) {
                aca[i] += __builtin_fabsf(xa[i][e] - ca[e]);
                aca[i] += __builtin_fabsf(xb[i][e] - cb[e]);
                acb[i] += __builtin_fabsf(xa[i + 4][e] - ca[e]);
                acb[i] += __builtin_fabsf(xb[i + 4][e] - cb[e]);
            }
        }
        // transpose: lane writes its 8 partials (slot = lane*12 + b, b128-aligned;
        // banks 12l%32 cover all 32 across 8 lanes -> balanced)
        *(f4*)&mypart[lane * 12]     = aca;
        *(f4*)&mypart[lane * 12 + 4] = acb;
        // lane reads partials of rows myb from lanes m = myo*8+j (broadcast reads:
        // 8 lanes sharing myb read the same address -> free)
        float s = 0.f;
#pragma unroll
        for (int j = 0; j < 8; ++j)
            s += mypart[(myo * 8 + j) * 12 + myb];
        // combine across the 8 myo-groups (lane bits 0..2)
        s += __shfl_xor(s, 1, 64);
        s += __shfl_xor(s, 2, 64);
        s += __shfl_xor(s, 4, 64);
        res = (myo == oc) ? s : res; // keep my column
    }

    // store: lane l -> S[(b0+myb)*DIM_O + o0+myo]; 8 contiguous 32B segments
    S[(b0 + myb) * DIM_O + o0 + myo] = res;

    // block max
    float m = res;
#pragma unroll
    for (int off = 32; off > 0; off >>= 1)
        m = fmaxf(m, __shfl_xor(m, off, 64));
    if (lane == 0) wmx[wv] = m;
    __syncthreads();
    if (tid == 0)
        bmax[blockIdx.x] = fmaxf(fmaxf(wmx[0], wmx[1]), fmaxf(wmx[2], wmx[3]));
}

__global__ __launch_bounds__(256) void k_out(float* __restrict__ S,
                                             const float* __restrict__ beta,
                                             const float* __restrict__ bmax)
{
    const int tid = threadIdx.x;
    const int lane = tid & 63;
    float m = 0.f;
#pragma unroll
    for (int i = 0; i < 32; ++i) // 2048 block maxes
        m = fmaxf(m, bmax[lane + 64 * i]);
#pragma unroll
    for (int off = 32; off > 0; off >>= 1)
        m = fmaxf(m, __shfl_xor(m, off, 64));
    const float shift = m * W_DIST;

    const int f = blockIdx.x * 256 + tid; // f4 index, 131072 total
    f4 s = ((const f4*)S)[f];
    f4 b = ((const f4*)beta)[f & 127];
    f4 r;
    r[0] = b[0] * (shift - s[0]);
    r[1] = b[1] * (shift - s[1]);
    r[2] = b[2] * (shift - s[2]);
    r[3] = b[3] * (shift - s[3]);
    ((f4*)S)[f] = r;
}

extern "C" void kernel_launch(void* const* d_in, const int* in_sizes, int n_in,
                              void* d_out, int out_size, void* d_ws, size_t ws_size,
                              hipStream_t stream) {
    const float* X = (const float*)d_in[0];
    const float* C = (const float*)d_in[1];
    const float* beta = (const float*)d_in[2];
    float* S = (float*)d_out;
    float* bmax = (float*)d_ws; // 2048 floats, fully overwritten each call
    k_sim<<<2048, 256, 0, stream>>>(X, C, S, bmax);
    k_out<<<512, 256, 0, stream>>>(S, beta, bmax);
}